// Round 9
// baseline (60.912 us; speedup 1.0000x reference)
//
#include <hip/hip_runtime.h>
#include <math.h>

// Problem constants (from reference)
constexpr int Hr = 64;
constexpr int Wr = 2048;
constexpr int Hb = 512;
constexpr int Wb = 512;
constexpr int B  = 4;
constexpr int C  = 64;
constexpr int BC = B * C;            // 256 channels
constexpr int NPIX = Hb * Wb;        // 262144 pixels

constexpr int TPB  = 512;            // threads per block (8 waves)
constexpr int HALF = NPIX / 2;       // 131072 pixels per block
constexpr int NIT  = HALF / 4 / TPB; // 64 iterations

typedef float f32x4 __attribute__((ext_vector_type(4)));
typedef int   i32x4 __attribute__((ext_vector_type(4)));

// py = 31.5 exactly -> rows 31,32 with wy = 0.5.
// px in float32 (identical arithmetic to R4..R8 -> absmax 0.0156 << 0.066).
// xi in [0,2046], xi+1 <= 2047.

// ---------------------------------------------------------------------------
// Kernel A: px lookup tables (xi: int, w: float). 262K atan2f total.
// ---------------------------------------------------------------------------
__global__ __launch_bounds__(256) void prep_px(
    i32x4* __restrict__ xig,          // [NPIX/4]
    f32x4* __restrict__ wg)           // [NPIX/4]
{
    const int g  = blockIdx.x * 256 + threadIdx.x;   // group index < NPIX/4
    const float cs = 50.0f / 255.5f;                    // R_MAX / (Hb/2 - 0.5)
    const float c1 = 2047.0f / 6.28318530717958647692f; // (Wr-1)/2pi
    const float c2 = 2047.0f / 2048.0f;                 // (Wr-1)/Wr
    i32x4 xo; f32x4 wo;
    #pragma unroll
    for (int j = 0; j < 4; ++j) {
        const int n = g * 4 + j;
        const float y = ((float)(n >> 9)  - 255.5f) * cs;
        const float x = ((float)(n & 511) - 255.5f) * cs;
        float phi = atan2f(y, x);
        phi = (phi < 0.0f) ? phi + 6.28318530717958647692f : phi;
        const float px = (2047.0f - phi * c1) * c2;   // in (0, 2046.01)
        const int   xi = (int)px;                     // px >= 0: trunc == floor
        xo[j] = xi;
        wo[j] = px - (float)xi;
    }
    xig[g] = xo;
    wg[g]  = wo;
}

// ---------------------------------------------------------------------------
// Kernel B: one block = half of one channel (512-KB contiguous output).
// Stage averaged row once (8 KB LDS, single barrier), then free-run:
// coalesced xi/w loads (L2-resident tables), ds_read2 gathers, NT stores
// marching linearly. No per-channel barriers -> no store-queue drains;
// fillBuffer-like write-stream locality.
// ---------------------------------------------------------------------------
__global__ __launch_bounds__(TPB) void sample_kernel(
    const float* __restrict__ rv,     // [B][C][Hr][Wr]
    const i32x4* __restrict__ xig,    // [NPIX/4]
    const f32x4* __restrict__ wg,     // [NPIX/4]
    float* __restrict__ out)          // [BC][NPIX]
{
    __shared__ float row[Wr];         // 8 KB

    const int half = blockIdx.x;      // 0..1
    const int ch   = blockIdx.y;      // 0..255
    const int tid  = threadIdx.x;     // 0..511

    // Stage averaged row: 512 f32x4 pairs, 512 threads -> exactly 1 each.
    {
        const float* chb = rv + (size_t)ch * (Hr * Wr) + (size_t)31 * Wr;
        const f32x4* r31 = (const f32x4*)chb;
        const f32x4* r32 = (const f32x4*)(chb + Wr);
        ((f32x4*)row)[tid] = r31[tid] * 0.5f + r32[tid] * 0.5f;
    }
    __syncthreads();                  // the only barrier

    const size_t g0 = (size_t)half * (HALF / 4);
    const i32x4* xs   = xig + g0;
    const f32x4* ws   = wg  + g0;
    f32x4*       out4 = (f32x4*)(out + (size_t)ch * NPIX) + g0;

    #pragma unroll 4
    for (int k = 0; k < NIT; ++k) {
        const int i = k * TPB + tid;
        const i32x4 xv = xs[i];
        const f32x4 wv = ws[i];
        f32x4 r;
        #pragma unroll
        for (int j = 0; j < 4; ++j) {
            const float a = row[xv[j]];
            const float b = row[xv[j] + 1];   // merges into ds_read2_b32
            r[j] = a + wv[j] * (b - a);       // sub + fmac
        }
        __builtin_nontemporal_store(r, out4 + i);
    }
}

extern "C" void kernel_launch(void* const* d_in, const int* in_sizes, int n_in,
                              void* d_out, int out_size, void* d_ws, size_t ws_size,
                              hipStream_t stream) {
    const float* rv_feat = (const float*)d_in[0];
    // d_in[1] (ref_bev) is unused by the reference computation.
    float* out = (float*)d_out;

    i32x4* xig = (i32x4*)d_ws;                         // NPIX/4 i32x4 = 1 MB
    f32x4* wg  = (f32x4*)((char*)d_ws + NPIX * 4);     // NPIX/4 f32x4 = 1 MB

    prep_px<<<dim3(NPIX / 4 / 256), dim3(256), 0, stream>>>(xig, wg);
    sample_kernel<<<dim3(2, BC), dim3(TPB), 0, stream>>>(rv_feat, xig, wg, out);
}

// Round 10
// 58.081 us; speedup vs baseline: 1.0487x; 1.0487x over previous
//
#include <hip/hip_runtime.h>
#include <math.h>

// Problem constants (from reference)
constexpr int Hr = 64;
constexpr int Wr = 2048;
constexpr int Hb = 512;
constexpr int Wb = 512;
constexpr int B  = 4;
constexpr int C  = 64;
constexpr int BC = B * C;            // 256 channels
constexpr int NPIX = Hb * Wb;        // 262144 pixels

constexpr int T = 8192;              // pixels per tile (per block)
constexpr int G = 8;                 // channels per block
constexpr int NTILE = NPIX / T;      // 32
constexpr int NCG   = BC / G;        // 32

typedef float f32x4 __attribute__((ext_vector_type(4)));

// py = 31.5 exactly -> rows 31,32 with wy = 0.5.
// px in float32: bilinear interp is continuous in px; ~1e-4 px error vs
// numpy's float64 path -> value error ~1e-3 << 0.066 threshold. The phi-wrap
// discontinuity at px=0 is ~0.64 px away from the nearest sample point, so
// float atan2f error cannot cross it; x0 in [0,2046], x0+1 <= 2047.
//
// R10 = R4 byte-identical EXCEPT: plain stores instead of nontemporal.
// A/B isolates the NT hint. Theory: NT bypasses L2 write-combining ->
// direct CU->HBM line writes cap at ~4.7 TB/s; plain stores drain via L2
// like fillBuffer (7 TB/s measured on this chip).

__global__ __launch_bounds__(256) void rv2bev_fused(
    const float* __restrict__ rv,    // [B][C][Hr][Wr]
    float* __restrict__ out)         // [B][C][Hb][Wb]
{
    __shared__ float rowbuf[2][Wr];  // 2 x 8 KB, double-buffered averaged row

    const int tile = blockIdx.x;     // 0..31
    const int cg   = blockIdx.y;     // 0..31
    const int tid  = threadIdx.x;

    // ---- per-block px computation: 32 pixels/thread, kept in registers ----
    int   x0[32];
    float wx[32];
    {
        const float cs = 50.0f / 255.5f;                    // R_MAX / (Hb/2 - 0.5)
        const float c1 = 2047.0f / 6.28318530717958647692f; // (Wr-1)/2pi
        const float c2 = 2047.0f / 2048.0f;                 // (Wr-1)/Wr
        #pragma unroll
        for (int k = 0; k < 8; ++k) {
            #pragma unroll
            for (int j = 0; j < 4; ++j) {
                const int n  = tile * T + (tid + k * 256) * 4 + j;  // global pixel
                const float y = ((float)(n >> 9)  - 255.5f) * cs;
                const float x = ((float)(n & 511) - 255.5f) * cs;
                float phi = atan2f(y, x);
                phi = (phi < 0.0f) ? phi + 6.28318530717958647692f : phi;
                const float px = (2047.0f - phi * c1) * c2;   // in (0, 2046.01)
                const float fx = floorf(px);
                x0[k * 4 + j] = (int)fx;                      // <= 2046
                wx[k * 4 + j] = px - fx;
            }
        }
    }

    // base of row 31, channel cg*G
    const float* rvb = rv + (size_t)(cg * G) * (Hr * Wr) + (size_t)31 * Wr;

    f32x4 sa0, sa1, sb0, sb1;        // staged rows for next channel

    // ---- prologue: stage channel 0 into rowbuf[0] ----
    {
        const f32x4* r31 = (const f32x4*)rvb;
        const f32x4* r32 = (const f32x4*)(rvb + Wr);
        sa0 = r31[tid]; sa1 = r31[tid + 256];
        sb0 = r32[tid]; sb1 = r32[tid + 256];
        f32x4* dst = (f32x4*)rowbuf[0];
        dst[tid]       = sa0 * 0.5f + sb0 * 0.5f;
        dst[tid + 256] = sa1 * 0.5f + sb1 * 0.5f;
    }

    for (int c = 0; c < G; ++c) {
        // T14 issue-early: launch next channel's global loads before the barrier
        if (c + 1 < G) {
            const float* chb = rvb + (size_t)(c + 1) * (Hr * Wr);
            const f32x4* r31 = (const f32x4*)chb;
            const f32x4* r32 = (const f32x4*)(chb + Wr);
            sa0 = r31[tid]; sa1 = r31[tid + 256];
            sb0 = r32[tid]; sb1 = r32[tid + 256];
        }
        __syncthreads();             // rowbuf[c&1] staged & prior gathers done

        const float* __restrict__ row = rowbuf[c & 1];
        f32x4* out4 = (f32x4*)(out + (size_t)(cg * G + c) * NPIX + (size_t)tile * T);
        #pragma unroll
        for (int k = 0; k < 8; ++k) {
            f32x4 r;
            #pragma unroll
            for (int j = 0; j < 4; ++j) {
                const int i = k * 4 + j;
                const float w = wx[i];
                r[j] = row[x0[i]] * (1.0f - w) + row[x0[i] + 1] * w;
            }
            out4[tid + k * 256] = r;          // PLAIN store (the A/B variable)
        }

        // write-late: LDS write of next channel after this channel's gathers
        if (c + 1 < G) {
            f32x4* dst = (f32x4*)rowbuf[(c + 1) & 1];
            dst[tid]       = sa0 * 0.5f + sb0 * 0.5f;
            dst[tid + 256] = sa1 * 0.5f + sb1 * 0.5f;
        }
    }
}

extern "C" void kernel_launch(void* const* d_in, const int* in_sizes, int n_in,
                              void* d_out, int out_size, void* d_ws, size_t ws_size,
                              hipStream_t stream) {
    const float* rv_feat = (const float*)d_in[0];
    // d_in[1] (ref_bev) is unused by the reference computation.
    float* out = (float*)d_out;

    rv2bev_fused<<<dim3(NTILE, NCG), dim3(256), 0, stream>>>(rv_feat, out);
}

// Round 11
// 57.705 us; speedup vs baseline: 1.0556x; 1.0065x over previous
//
#include <hip/hip_runtime.h>
#include <math.h>

// Problem constants (from reference)
constexpr int Hr = 64;
constexpr int Wr = 2048;
constexpr int Hb = 512;
constexpr int Wb = 512;
constexpr int B  = 4;
constexpr int C  = 64;
constexpr int BC = B * C;            // 256 channels
constexpr int NPIX = Hb * Wb;        // 262144 pixels

constexpr int T = 8192;              // pixels per tile (per block)
constexpr int G = 8;                 // channels per block
constexpr int NTILE = NPIX / T;      // 32
constexpr int NCG   = BC / G;        // 32

constexpr int WPAD = Wr + Wr / 32;   // 2112 floats: +1 pad every 32

typedef float f32x4 __attribute__((ext_vector_type(4)));

// py = 31.5 exactly -> rows 31,32 with wy = 0.5.
// px in float32 (identical arithmetic to R4..R10 -> absmax 0.0156 << 0.066).
//
// R11 = R10 skeleton + PADDED LDS layout addr(x) = x + (x>>5).
// Rationale: lanes are 4 BEV-pixels apart; xi stride between lanes is ~4-16
// -> raw layout is an 8-to-32-way bank conflict on every gather (the
// invariant ~42us/CU LDS wall across R3..R10). The +1-per-32 pad rotates
// bank residues so all pow-2 strides spread over all 32 banks (<=2/bank).
// Both padded addresses are precomputed once and packed into one int.

__global__ __launch_bounds__(256) void rv2bev_fused(
    const float* __restrict__ rv,    // [B][C][Hr][Wr]
    float* __restrict__ out)         // [B][C][Hb][Wb]
{
    __shared__ float rowbuf[2][WPAD];  // 2 x 8448 B, double-buffered

    const int tile = blockIdx.x;     // 0..31
    const int cg   = blockIdx.y;     // 0..31
    const int tid  = threadIdx.x;

    int   pk[32];                    // packed padded addrs: a0 | (a1<<16)
    float wx[32];

    // base of row 31, channel cg*G
    const float* rvb = rv + (size_t)(cg * G) * (Hr * Wr) + (size_t)31 * Wr;

    f32x4 sa0, sa1, sb0, sb1;        // staged rows for next channel

    // scalar padded stage of one f32x4 group g (floats x=4g..4g+3; never
    // crosses a pad since 32 % 4 == 0). Write stride 4+pad -> conflict-free.
    auto stage4 = [&](float* dst, const f32x4 v, const int g) {
        const int base = 4 * g + ((4 * g) >> 5);
        dst[base + 0] = v.x; dst[base + 1] = v.y;
        dst[base + 2] = v.z; dst[base + 3] = v.w;
    };

    // ---- prologue: stage channel 0 into rowbuf[0] ----
    {
        const f32x4* r31 = (const f32x4*)rvb;
        const f32x4* r32 = (const f32x4*)(rvb + Wr);
        sa0 = r31[tid]; sa1 = r31[tid + 256];
        sb0 = r32[tid]; sb1 = r32[tid + 256];
        stage4(rowbuf[0], sa0 * 0.5f + sb0 * 0.5f, tid);
        stage4(rowbuf[0], sa1 * 0.5f + sb1 * 0.5f, tid + 256);
    }

    const float cs = 50.0f / 255.5f;                    // R_MAX / (Hb/2 - 0.5)
    const float c1 = 2047.0f / 6.28318530717958647692f; // (Wr-1)/2pi
    const float c2 = 2047.0f / 2048.0f;                 // (Wr-1)/Wr

    for (int c = 0; c < G; ++c) {
        // issue-early: next channel's global loads before the barrier
        if (c + 1 < G) {
            const float* chb = rvb + (size_t)(c + 1) * (Hr * Wr);
            const f32x4* r31 = (const f32x4*)chb;
            const f32x4* r32 = (const f32x4*)(chb + Wr);
            sa0 = r31[tid]; sa1 = r31[tid + 256];
            sb0 = r32[tid]; sb1 = r32[tid + 256];
        }
        __syncthreads();             // rowbuf[c&1] staged & prior gathers done

        const float* __restrict__ row = rowbuf[c & 1];
        f32x4* out4 = (f32x4*)(out + (size_t)(cg * G + c) * NPIX + (size_t)tile * T);

        if (c == 0) {
            // compute px inline; save packed padded addrs + weights
            #pragma unroll
            for (int k = 0; k < 8; ++k) {
                f32x4 r;
                #pragma unroll
                for (int j = 0; j < 4; ++j) {
                    const int i = k * 4 + j;
                    const int n  = tile * T + (tid + k * 256) * 4 + j;
                    const float y = ((float)(n >> 9)  - 255.5f) * cs;
                    const float x = ((float)(n & 511) - 255.5f) * cs;
                    float phi = atan2f(y, x);
                    phi = (phi < 0.0f) ? phi + 6.28318530717958647692f : phi;
                    const float px = (2047.0f - phi * c1) * c2;   // (0, 2046.01)
                    const float fx = floorf(px);
                    const int   xi = (int)fx;                     // <= 2046
                    const float w  = px - fx;
                    const int a0 = xi + (xi >> 5);
                    const int x1 = xi + 1;
                    const int a1 = x1 + (x1 >> 5);
                    pk[i] = a0 | (a1 << 16);
                    wx[i] = w;
                    const float A  = row[a0];
                    const float Bv = row[a1];
                    r[j] = A + w * (Bv - A);
                }
                out4[tid + k * 256] = r;
            }
        } else {
            #pragma unroll
            for (int k = 0; k < 8; ++k) {
                f32x4 r;
                #pragma unroll
                for (int j = 0; j < 4; ++j) {
                    const int i = k * 4 + j;
                    const int p = pk[i];
                    const float A  = row[p & 0xFFFF];
                    const float Bv = row[p >> 16];
                    r[j] = A + wx[i] * (Bv - A);
                }
                out4[tid + k * 256] = r;
            }
        }

        // write-late: LDS write of next channel after this channel's gathers
        if (c + 1 < G) {
            float* dst = rowbuf[(c + 1) & 1];
            stage4(dst, sa0 * 0.5f + sb0 * 0.5f, tid);
            stage4(dst, sa1 * 0.5f + sb1 * 0.5f, tid + 256);
        }
    }
}

extern "C" void kernel_launch(void* const* d_in, const int* in_sizes, int n_in,
                              void* d_out, int out_size, void* d_ws, size_t ws_size,
                              hipStream_t stream) {
    const float* rv_feat = (const float*)d_in[0];
    // d_in[1] (ref_bev) is unused by the reference computation.
    float* out = (float*)d_out;

    rv2bev_fused<<<dim3(NTILE, NCG), dim3(256), 0, stream>>>(rv_feat, out);
}